// Round 15
// baseline (250.796 us; speedup 1.0000x reference)
//
#include <hip/hip_runtime.h>
#include <hip/hip_bf16.h>
#include <stdint.h>

// Problem constants (B=2, S=2048, D=1024, H=16, DK=64, FF=4096)
#define B_   2
#define S_   2048
#define D_   1024
#define H_   16
#define FF_  4096
#define TOK  4096        // B*S
#define EPS_ 1e-5f
#define SC2  0.18033688f  // (1/8) * log2(e) -- folded into Q at projection

typedef __attribute__((ext_vector_type(8))) short short8;
typedef __attribute__((ext_vector_type(4))) short short4_t;
typedef __attribute__((ext_vector_type(4))) float float4_t;

__device__ __forceinline__ short f2bf(float f) {
  union { float f; uint32_t u; } v; v.f = f;
  uint32_t r = v.u + 0x7fffu + ((v.u >> 16) & 1u);
  return (short)(r >> 16);
}

__device__ __forceinline__ float bf2f(short s) {
  union { uint32_t u; float f; } v; v.u = ((uint32_t)(uint16_t)s) << 16; return v.f;
}

// packed f32x2 -> bf16x2 (compiler emits v_cvt_pk_bf16_f32; RNE)
__device__ __forceinline__ uint32_t pkbf(float a, float b) {
  __hip_bfloat162 h = __float22bfloat162_rn(make_float2(a, b));   // x=low=a
  union { __hip_bfloat162 h; uint32_t u; } c; c.h = h; return c.u;
}

__device__ __forceinline__ void gload_lds16(const void* g, void* l) {
  __builtin_amdgcn_global_load_lds(
      (const __attribute__((address_space(1))) void*)g,
      (__attribute__((address_space(3))) void*)l, 16, 0, 0);
}

// ---------------- fused prep: LN1 + mask + weight-cvt (independent work) ---
// blocks [0,4096): LN1 row per block; [4096,4112): mask (256 thr = 4 tiles);
// [4112,5648): grid-stride bf16 conversion of all weights (12M shorts).
__global__ __launch_bounds__(256) void prep_kernel(
    const float* __restrict__ x, const float* __restrict__ ln1a,
    const float* __restrict__ ln1b, short* __restrict__ h1,
    const int* __restrict__ m, float* __restrict__ maskb, int* __restrict__ flags,
    const float* __restrict__ wq, const float* __restrict__ wk,
    const float* __restrict__ wv, const float* __restrict__ wo,
    const float* __restrict__ f1, const float* __restrict__ f2,
    short* __restrict__ wout)
{
  const int blk = blockIdx.x;
  const int tid = threadIdx.x;
  if (blk < TOK) {
    // ---- LN1 (ddof=1, divide by std+eps) ----
    const int row = blk;
    const float4_t v = *(const float4_t*)(x + (size_t)row * D_ + tid * 4);
    float s  = v[0] + v[1] + v[2] + v[3];
    float ss = v[0]*v[0] + v[1]*v[1] + v[2]*v[2] + v[3]*v[3];
    #pragma unroll
    for (int mm = 1; mm < 64; mm <<= 1) { s += __shfl_xor(s, mm); ss += __shfl_xor(ss, mm); }
    __shared__ float red[8];
    const int wave = tid >> 6, lane = tid & 63;
    if (lane == 0) { red[wave] = s; red[4 + wave] = ss; }
    __syncthreads();
    s  = red[0] + red[1] + red[2] + red[3];
    ss = red[4] + red[5] + red[6] + red[7];
    const float mean = s * (1.0f / D_);
    float var = (ss - (float)D_ * mean * mean) * (1.0f / (D_ - 1));
    var = fmaxf(var, 0.0f);
    const float inv = 1.0f / (sqrtf(var) + EPS_);
    short4_t o;
    #pragma unroll
    for (int j = 0; j < 4; j++) {
      float a = ln1a[tid*4 + j], bb = ln1b[tid*4 + j];
      o[j] = f2bf((v[j] - mean) * inv * a + bb);
    }
    *(short4_t*)(h1 + (size_t)row * D_ + tid * 4) = o;
  } else if (blk < TOK + 16) {
    // ---- mask bias + per-64-key-tile flags (one wave = one tile) ----
    const int i = (blk - TOK) * 256 + tid;
    const int mv = m[i];
    maskb[i] = mv ? 0.0f : -1e30f;
    unsigned long long bal = __ballot(mv == 0);
    if ((tid & 63) == 0) flags[i >> 6] = (bal != 0ull) ? 1 : 0;
  } else {
    // ---- weights -> bf16, grid-stride over 12M shorts ----
    const int n4 = (12 << 20) / 4;
    const int nb = gridDim.x - TOK - 16;
    int idx = (blk - TOK - 16) * 256 + tid;
    const int stride = nb * 256;
    for (int j4 = idx; j4 < n4; j4 += stride) {
      const int j = j4 * 4;
      const int seg = j >> 20;
      const float* src; int off;
      if (seg < 4)      { src = (seg == 0) ? wq : (seg == 1) ? wk : (seg == 2) ? wv : wo;
                          off = j & ((1 << 20) - 1); }
      else if (seg < 8) { src = f1; off = j - (4 << 20); }
      else              { src = f2; off = j - (8 << 20); }
      float4_t v = *(const float4_t*)(src + off);
      short4_t o = { f2bf(v[0]), f2bf(v[1]), f2bf(v[2]), f2bf(v[3]) };
      *(short4_t*)(wout + j) = o;
    }
  }
}

// --------- final combine: out = x2 + bias + bf16(p0)+bf16(p1)+bf16(p2) + out
__global__ void combine3_kernel(const float* __restrict__ x2,
                                const short* __restrict__ pA,   // z0 | z1
                                const short* __restrict__ pB,   // z2
                                float* __restrict__ out, const float* __restrict__ bias,
                                int n) {
  int idx = blockIdx.x * blockDim.x + threadIdx.x;
  int stride = gridDim.x * blockDim.x;
  for (int j = idx * 4; j < n; j += stride * 4) {
    float4_t a  = *(const float4_t*)(x2 + j);
    float4_t c  = *(const float4_t*)(out + j);
    float4_t bb = *(const float4_t*)(bias + (j & (D_ - 1)));
    short4_t q0 = *(const short4_t*)(pA + j);
    short4_t q1 = *(const short4_t*)(pA + (4u << 20) + j);
    short4_t q2 = *(const short4_t*)(pB + j);
    float4_t o;
    #pragma unroll
    for (int e = 0; e < 4; e++)
      o[e] = a[e] + c[e] + bb[e] + bf2f(q0[e]) + bf2f(q1[e]) + bf2f(q2[e]);
    *(float4_t*)(out + j) = o;
  }
}

// ---------------- LayerNorm (LN2), f32 in, bf16 out ------------------------
__global__ __launch_bounds__(256) void ln_kernel(
    const float* __restrict__ x, const float* __restrict__ alpha,
    const float* __restrict__ beta, short* __restrict__ out)
{
  const int row = blockIdx.x;
  const int tid = threadIdx.x;
  const float4_t v = *(const float4_t*)(x + (size_t)row * D_ + tid * 4);
  float s  = v[0] + v[1] + v[2] + v[3];
  float ss = v[0]*v[0] + v[1]*v[1] + v[2]*v[2] + v[3]*v[3];
  #pragma unroll
  for (int m = 1; m < 64; m <<= 1) { s += __shfl_xor(s, m); ss += __shfl_xor(ss, m); }
  __shared__ float red[8];
  const int wave = tid >> 6, lane = tid & 63;
  if (lane == 0) { red[wave] = s; red[4 + wave] = ss; }
  __syncthreads();
  s  = red[0] + red[1] + red[2] + red[3];
  ss = red[4] + red[5] + red[6] + red[7];
  const float mean = s * (1.0f / D_);
  float var = (ss - (float)D_ * mean * mean) * (1.0f / (D_ - 1));
  var = fmaxf(var, 0.0f);
  const float inv = 1.0f / (sqrtf(var) + EPS_);
  short4_t o;
  #pragma unroll
  for (int j = 0; j < 4; j++) {
    float a = alpha[tid*4 + j], bb = beta[tid*4 + j];
    o[j] = f2bf((v[j] - mean) * inv * a + bb);
  }
  *(short4_t*)(out + (size_t)row * D_ + tid * 4) = o;
}

// ---------------- 128-tile GEMM (r6 2-buffer structure; WO only) -----------
template<int EPI, int BN>
__global__ __launch_bounds__(256) void gemm_bt(
    const short* __restrict__ A, const short* __restrict__ Bm,
    void* __restrict__ Cout, void* __restrict__ Cout2,
    const float* __restrict__ bias, const float* __restrict__ res,
    int N, int K, int lda, int ldb)
{
  __shared__ __align__(16) short As[2][128][32];
  __shared__ __align__(16) short Bs[2][BN][32];

  const int tid  = threadIdx.x;
  const int wave = tid >> 6, lane = tid & 63;
  const int l15  = lane & 15, l4 = lane >> 4;

  const int gx = gridDim.x, gy = gridDim.y;
  int bid = (blockIdx.z * gy + blockIdx.y) * gx + blockIdx.x;
  const int q8 = (gx * gy * gridDim.z) >> 3;
  bid = (bid & 7) * q8 + (bid >> 3);
  const int n0 = (bid % gx) * BN;
  const int m0 = ((bid / gx) % gy) * 128;
  const int zi = bid / (gx * gy);
  const int koff = zi * K;

  constexpr int MI = (BN == 128) ? 4 : 2;
  const int rb = (BN == 128) ? (wave >> 1) * 64 : wave * 32;
  const int cb = (BN == 128) ? (wave & 1) * 64 : 0;

  float4_t acc[MI][4] = {};

  const int scol = (lane & 3) * 8;
  const short* gA0 = A + (size_t)(m0 + wave*32 + (lane >> 2)) * lda + koff + scol;
  const short* gA1 = gA0 + (size_t)16 * lda;
  const short* gB0;
  const short* gB1 = nullptr;
  if (BN == 128) {
    gB0 = Bm + (size_t)(n0 + wave*32 + (lane >> 2)) * ldb + koff + scol;
    gB1 = gB0 + (size_t)16 * ldb;
  } else {
    gB0 = Bm + (size_t)(n0 + wave*16 + (lane >> 2)) * ldb + koff + scol;
  }

  gload_lds16(gA0, &As[0][wave*32][0]);
  gload_lds16(gA1, &As[0][wave*32 + 16][0]);
  if (BN == 128) {
    gload_lds16(gB0, &Bs[0][wave*32][0]);
    gload_lds16(gB1, &Bs[0][wave*32 + 16][0]);
  } else {
    gload_lds16(gB0, &Bs[0][wave*16][0]);
  }

  for (int k0 = 0; k0 < K; k0 += 32) {
    const int cur = (k0 >> 5) & 1;
    __syncthreads();
    if (k0 + 32 < K) {
      gload_lds16(gA0 + k0 + 32, &As[cur^1][wave*32][0]);
      gload_lds16(gA1 + k0 + 32, &As[cur^1][wave*32 + 16][0]);
      if (BN == 128) {
        gload_lds16(gB0 + k0 + 32, &Bs[cur^1][wave*32][0]);
        gload_lds16(gB1 + k0 + 32, &Bs[cur^1][wave*32 + 16][0]);
      } else {
        gload_lds16(gB0 + k0 + 32, &Bs[cur^1][wave*16][0]);
      }
    }
    short8 af[MI], bf[4];
    #pragma unroll
    for (int i = 0; i < MI; i++)
      af[i] = *(const short8*)&As[cur][rb + i*16 + l15][l4*8];
    #pragma unroll
    for (int i = 0; i < 4; i++)
      bf[i] = *(const short8*)&Bs[cur][cb + i*16 + l15][l4*8];
    #pragma unroll
    for (int mi = 0; mi < MI; mi++)
      #pragma unroll
      for (int ni = 0; ni < 4; ni++)
        acc[mi][ni] = __builtin_amdgcn_mfma_f32_16x16x32_bf16(af[mi], bf[ni], acc[mi][ni], 0, 0, 0);
  }

  const int crow0 = m0 + rb + l4*4;
  const int ccol0 = n0 + cb + l15;
  #pragma unroll
  for (int mi = 0; mi < MI; mi++) {
    #pragma unroll
    for (int ni = 0; ni < 4; ni++) {
      const int col = ccol0 + ni*16;
      const float bc = bias[col];
      #pragma unroll
      for (int r = 0; r < 4; r++) {
        const int row = crow0 + mi*16 + r;
        ((float*)Cout)[(size_t)row * N + col] =
            res[(size_t)row * N + col] + acc[mi][ni][r] + bc;
      }
    }
  }
}

// ============================================================================
// 256x256-tile GEMM core (verified r13/r14)
// ============================================================================
#define G256_DECLS                                                            \
  const int tid = threadIdx.x;                                                \
  const int w = tid >> 6, lane = tid & 63;                                    \
  const int wm = w >> 2, wn = w & 3;                                          \
  const int l15 = lane & 15, l4 = lane >> 4;                                  \
  const int srow = w*8 + (lane >> 3);                                         \
  const int schk = ((lane & 7) ^ (((lane >> 5) & 1) << 1)) * 8;               \
  const int rswz = (l4 ^ (((l15 >> 2) & 1) << 1)) * 8;                        \
  const int aoff = (wm*128 + l15) * 64 + rswz;                                \
  const int boff = (wn*64  + l15) * 64 + rswz;

#define G256_STG(buf_, koff_, LDA_) do {                                      \
    short* da = lds + (buf_)*16384 + w*512;                                   \
    short* db = lds + 32768 + (buf_)*16384 + w*512;                           \
    const short* sa = gA + (koff_);                                           \
    const short* sb = gB + (koff_);                                           \
    gload_lds16(sa,                      da);                                 \
    gload_lds16(sa +  64*(size_t)(LDA_), da + 4096);                          \
    gload_lds16(sa + 128*(size_t)(LDA_), da + 8192);                          \
    gload_lds16(sa + 192*(size_t)(LDA_), da + 12288);                         \
    gload_lds16(sb,                      db);                                 \
    gload_lds16(sb +  64*(size_t)(LDA_), db + 4096);                          \
    gload_lds16(sb + 128*(size_t)(LDA_), db + 8192);                          \
    gload_lds16(sb + 192*(size_t)(LDA_), db + 12288);                         \
  } while (0)

#define G256_LOOP(LDA_)                                                       \
  float4_t acc[8][4] = {};                                                    \
  G256_STG(0, 0, LDA_);                                                       \
  G256_STG(1, 64, LDA_);                                                      \
  for (int t = 0; t < 16; ++t) {                                              \
    const int cur = t & 1;                                                    \
    if (t < 15) asm volatile("s_waitcnt vmcnt(8)" ::: "memory");              \
    else        asm volatile("s_waitcnt vmcnt(0)" ::: "memory");              \
    __builtin_amdgcn_s_barrier();                                             \
    __builtin_amdgcn_sched_barrier(0);                                        \
    const short* La = lds + cur*16384 + aoff;                                 \
    const short* Lb = lds + 32768 + cur*16384 + boff;                         \
    short8 af[4][2], bf0[2][2], bf1[2][2];                                    \
    _Pragma("unroll") for (int mf = 0; mf < 4; mf++)                          \
      _Pragma("unroll") for (int ks = 0; ks < 2; ks++)                        \
        af[mf][ks] = *(const short8*)(La + mf*1024 + ks*32);                  \
    _Pragma("unroll") for (int nf = 0; nf < 2; nf++)                          \
      _Pragma("unroll") for (int ks = 0; ks < 2; ks++)                        \
        bf0[nf][ks] = *(const short8*)(Lb + nf*1024 + ks*32);                 \
    _Pragma("unroll") for (int nf = 0; nf < 2; nf++)                          \
      _Pragma("unroll") for (int ks = 0; ks < 2; ks++)                        \
        bf1[nf][ks] = *(const short8*)(Lb + (2+nf)*1024 + ks*32);             \
    __builtin_amdgcn_s_setprio(1);                                            \
    _Pragma("unroll") for (int mf = 0; mf < 4; mf++)                          \
      _Pragma("unroll") for (int nf = 0; nf < 2; nf++)                        \
        _Pragma("unroll") for (int ks = 0; ks < 2; ks++)                      \
          acc[mf][nf] = __builtin_amdgcn_mfma_f32_16x16x32_bf16(              \
              af[mf][ks], bf0[nf][ks], acc[mf][nf], 0, 0, 0);                 \
    __builtin_amdgcn_s_setprio(0);                                            \
    short8 a2[4][2];                                                          \
    _Pragma("unroll") for (int mf = 0; mf < 4; mf++)                          \
      _Pragma("unroll") for (int ks = 0; ks < 2; ks++)                        \
        a2[mf][ks] = *(const short8*)(La + (4+mf)*1024 + ks*32);              \
    __builtin_amdgcn_s_setprio(1);                                            \
    _Pragma("unroll") for (int mf = 0; mf < 4; mf++)                          \
      _Pragma("unroll") for (int nf = 0; nf < 2; nf++)                        \
        _Pragma("unroll") for (int ks = 0; ks < 2; ks++)                      \
          acc[mf][2+nf] = __builtin_amdgcn_mfma_f32_16x16x32_bf16(            \
              af[mf][ks], bf1[nf][ks], acc[mf][2+nf], 0, 0, 0);               \
    _Pragma("unroll") for (int mf = 0; mf < 4; mf++)                          \
      _Pragma("unroll") for (int nf = 0; nf < 2; nf++)                        \
        _Pragma("unroll") for (int ks = 0; ks < 2; ks++)                      \
          acc[4+mf][2+nf] = __builtin_amdgcn_mfma_f32_16x16x32_bf16(          \
              a2[mf][ks], bf1[nf][ks], acc[4+mf][2+nf], 0, 0, 0);             \
    __builtin_amdgcn_s_setprio(0);                                            \
    __builtin_amdgcn_s_barrier();   /* all waves done reading buf[cur] */     \
    if (t < 14) G256_STG(cur, (t+2)*64, LDA_);                                \
    __builtin_amdgcn_s_setprio(1);                                            \
    _Pragma("unroll") for (int mf = 0; mf < 4; mf++)                          \
      _Pragma("unroll") for (int nf = 0; nf < 2; nf++)                        \
        _Pragma("unroll") for (int ks = 0; ks < 2; ks++)                      \
          acc[4+mf][nf] = __builtin_amdgcn_mfma_f32_16x16x32_bf16(            \
              a2[mf][ks], bf0[nf][ks], acc[4+mf][nf], 0, 0, 0);               \
    __builtin_amdgcn_s_setprio(0);                                            \
  }

// ---------------- FF1 at 256^2: relu(A @ B^T + bias) -> bf16 ---------------
__global__ __launch_bounds__(512, 2) void ff1_256(
    const short* __restrict__ A, const short* __restrict__ Bm,
    short* __restrict__ Cout, const float* __restrict__ bias)
{
  __shared__ __align__(16) short lds[65536];   // 128 KB
  G256_DECLS
  const int gx = gridDim.x;
  int bid = blockIdx.y * gx + blockIdx.x;
  const int q8 = (gx * gridDim.y) >> 3;
  bid = (bid & 7) * q8 + (bid >> 3);
  const int n0 = (bid % gx) * 256;
  const int m0 = (bid / gx) * 256;
  const short* gA = A  + (size_t)(m0 + srow) * 1024 + schk;
  const short* gB = Bm + (size_t)(n0 + srow) * 1024 + schk;

  G256_LOOP(1024)

  #pragma unroll
  for (int mf = 0; mf < 8; mf++) {
    #pragma unroll
    for (int nf = 0; nf < 4; nf++) {
      const int col = n0 + wn*64 + nf*16 + l15;
      const float bc = bias[col];
      #pragma unroll
      for (int r = 0; r < 4; r++) {
        const int row = m0 + wm*128 + mf*16 + l4*4 + r;
        Cout[(size_t)row * FF_ + col] = f2bf(fmaxf(acc[mf][nf][r] + bc, 0.0f));
      }
    }
  }
}

// ---------------- QKV at 256^2: [Q|K|V] = h1 @ wqkv^T + bias ---------------
__global__ __launch_bounds__(512, 2) void qkv_256(
    const short* __restrict__ A, const short* __restrict__ Bm,
    short* __restrict__ qkbuf, short* __restrict__ vt,
    const float* __restrict__ qb, const float* __restrict__ kb,
    const float* __restrict__ vb)
{
  __shared__ __align__(16) short lds[65536];
  G256_DECLS
  const int gx = gridDim.x;   // 12
  int bid = blockIdx.y * gx + blockIdx.x;
  const int q8 = (gx * gridDim.y) >> 3;
  bid = (bid & 7) * q8 + (bid >> 3);
  const int n0 = (bid % gx) * 256;
  const int m0 = (bid / gx) * 256;
  const short* gA = A  + (size_t)(m0 + srow) * 1024 + schk;
  const short* gB = Bm + (size_t)(n0 + srow) * 1024 + schk;

  G256_LOOP(1024)

  const int seg = n0 >> 10;   // 0=Q, 1=K, 2=V (uniform per block)
  if (seg < 2) {
    const float* bb = seg ? kb : qb;
    const float scl = seg ? 1.0f : SC2;
    #pragma unroll
    for (int mf = 0; mf < 8; mf++)
      #pragma unroll
      for (int nf = 0; nf < 4; nf++) {
        const int col = n0 + wn*64 + nf*16 + l15;
        const float bc = bb[col & 1023];
        #pragma unroll
        for (int r = 0; r < 4; r++) {
          const int row = m0 + wm*128 + mf*16 + l4*4 + r;
          qkbuf[(size_t)row * 2048 + col] = f2bf((acc[mf][nf][r] + bc) * scl);
        }
      }
  } else {
    #pragma unroll
    for (int mf = 0; mf < 8; mf++)
      #pragma unroll
      for (int nf = 0; nf < 4; nf++) {
        const int d = n0 + wn*64 + nf*16 + l15 - 2048;
        const float bc = vb[d];
        const int row0 = m0 + wm*128 + mf*16 + l4*4;
        short4_t o = { f2bf(acc[mf][nf][0] + bc), f2bf(acc[mf][nf][1] + bc),
                       f2bf(acc[mf][nf][2] + bc), f2bf(acc[mf][nf][3] + bc) };
        *(short4_t*)&vt[(size_t)d * TOK + row0] = o;
      }
  }
}

// ---------------- FF2 at 256^2, split-K=4 ----------------------------------
__global__ __launch_bounds__(512, 2) void ff2_256(
    const short* __restrict__ A, const short* __restrict__ Bm,
    short* __restrict__ pA, short* __restrict__ pB, float* __restrict__ dout)
{
  __shared__ __align__(16) short lds[65536];
  G256_DECLS
  const int gx = gridDim.x, gy = gridDim.y;   // 4, 16
  int bid = (blockIdx.z * gy + blockIdx.y) * gx + blockIdx.x;
  const int q8 = (gx * gy * gridDim.z) >> 3;
  bid = (bid & 7) * q8 + (bid >> 3);
  const int n0 = (bid % gx) * 256;
  const int m0 = ((bid / gx) % gy) * 256;
  const int zi = bid / (gx * gy);
  const short* gA = A  + (size_t)(m0 + srow) * 4096 + zi*1024 + schk;
  const short* gB = Bm + (size_t)(n0 + srow) * 4096 + zi*1024 + schk;

  G256_LOOP(4096)

  if (zi < 3) {
    short* dst = (zi < 2) ? (pA + (size_t)zi * (4u << 20)) : pB;
    #pragma unroll
    for (int mf = 0; mf < 8; mf++)
      #pragma unroll
      for (int nf = 0; nf < 4; nf++) {
        const int col = n0 + wn*64 + nf*16 + l15;
        #pragma unroll
        for (int r = 0; r < 4; r++) {
          const int row = m0 + wm*128 + mf*16 + l4*4 + r;
          dst[(size_t)row * D_ + col] = f2bf(acc[mf][nf][r]);
        }
      }
  } else {
    #pragma unroll
    for (int mf = 0; mf < 8; mf++)
      #pragma unroll
      for (int nf = 0; nf < 4; nf++) {
        const int col = n0 + wn*64 + nf*16 + l15;
        #pragma unroll
        for (int r = 0; r < 4; r++) {
          const int row = m0 + wm*128 + mf*16 + l4*4 + r;
          dout[(size_t)row * D_ + col] = acc[mf][nf][r];
        }
      }
  }
}

// ---------------- Flash attention (r14 structure, 5 blocks/CU) -------------
__global__ __launch_bounds__(256, 5) void attn_kernel(
    const short* __restrict__ qk, const short* __restrict__ vt,
    const float* __restrict__ maskb, const int* __restrict__ mflags,
    short* __restrict__ out)
{
  int bid = (blockIdx.z * H_ + blockIdx.y) * (S_/64) + blockIdx.x;
  bid = (bid & 7) * ((B_ * H_ * (S_/64)) >> 3) + (bid >> 3);
  const int qt = bid % (S_/64);
  const int h  = (bid / (S_/64)) % H_;
  const int b  = bid / ((S_/64) * H_);

  const int tid = threadIdx.x, wave = tid >> 6, lane = tid & 63;
  const int l15 = lane & 15, l4 = lane >> 4;
  const int q0 = qt * 64 + wave * 16;

  __shared__ __align__(16) short Kt[2][4096];
  __shared__ __align__(16) short Vt[2][4096];

  short8 qa[2];
  #pragma unroll
  for (int kc = 0; kc < 2; kc++)
    qa[kc] = *(const short8*)&qk[(size_t)(b*S_ + q0 + l15) * 2048 + h*64 + kc*32 + l4*8];

  short8 ones;
  #pragma unroll
  for (int i = 0; i < 8; i++) ones[i] = (short)0x3F80;

  float4_t acc[4];
  #pragma unroll
  for (int dg = 0; dg < 4; dg++) acc[dg] = (float4_t){0.f, 0.f, 0.f, 0.f};
  float4_t accl = (float4_t){0.f, 0.f, 0.f, 0.f};
  float m2 = 0.0f;

  const int r8 = lane >> 3;
  const int ch = (lane & 7) ^ ((r8 & 3) | ((wave & 1) << 2));
  const int sbase = wave * 512;

  #pragma unroll
  for (int i = 0; i < 2; i++) {
    const int row = i*32 + wave*8 + r8;
    gload_lds16(qk + (size_t)(b*S_ + row) * 2048 + 1024 + h*64 + ch*8, &Kt[0][sbase + i*2048]);
    gload_lds16(vt + (size_t)(h*64 + row) * TOK + b*S_ + ch*8,         &Vt[0][sbase + i*2048]);
  }

  int krow[4];
  #pragma unroll
  for (int kg = 0; kg < 4; kg++)
    krow[kg] = 32*(kg>>1) + 8*(l15>>2) + 4*(kg&1) + (l15&3);
  const int gq = (l15 & 3) | (((l15 >> 2) & 1) << 2);
  const int gv = (l15 & 3) | (((l15 >> 3) & 1) << 2);

  for (int t = 0; t < S_/64; t++) {
    const int cur = t & 1;
    __syncthreads();
    if (t + 1 < S_/64) {
      const int k1 = (t + 1) * 64;
      #pragma unroll
      for (int i = 0; i < 2; i++) {
        const int row = i*32 + wave*8 + r8;
        gload_lds16(qk + (size_t)(b*S_ + k1 + row) * 2048 + 1024 + h*64 + ch*8, &Kt[cur^1][sbase + i*2048]);
        gload_lds16(vt + (size_t)(h*64 + row) * TOK + b*S_ + k1 + ch*8,         &Vt[cur^1][sbase + i*2048]);
      }
    }
    const short* Kc = &Kt[cur][0];
    const short* Vc = &Vt[cur][0];

    short8 kf[4][2], vf[4][2];
    #pragma unroll
    for (int kg = 0; kg < 4; kg++)
      #pragma unroll
      for (int kc = 0; kc < 2; kc++)
        kf[kg][kc] = *(const short8*)(Kc + krow[kg]*64 + ((l4 + kc*4) ^ gq) * 8);
    #pragma unroll
    for (int dg = 0; dg < 4; dg++)
      #pragma unroll
      for (int pc = 0; pc < 2; pc++)
        vf[dg][pc] = *(const short8*)(Vc + (dg*16 + l15)*64 + ((l4 + pc*4) ^ gv) * 8);

    const float negm2 = -m2;
    float4_t sc[4];
    #pragma unroll
    for (int kg = 0; kg < 4; kg++)
      sc[kg] = (float4_t){negm2, negm2, negm2, negm2};
    __builtin_amdgcn_s_setprio(1);
    #pragma unroll
    for (int kg = 0; kg < 4; kg++)
      #pragma unroll
      for (int kc = 0; kc < 2; kc++)
        sc[kg] = __builtin_amdgcn_mfma_f32_16x16x32_bf16(kf[kg][kc], qa[kc], sc[kg], 0, 0, 0);
    __builtin_amdgcn_s_setprio(0);

    if (mflags[b*(S_/64) + t]) {
      #pragma unroll
      for (int kg = 0; kg < 4; kg++) {
        float4_t mb = *(const float4_t*)&maskb[b*S_ + t*64 + 32*(kg>>1) + 4*(kg&1) + 8*l4];
        #pragma unroll
        for (int r = 0; r < 4; r++) sc[kg][r] += mb[r];
      }
    }

    float pm = fmaxf(fmaxf(sc[0][0], sc[0][1]), sc[0][2]);
    pm = fmaxf(fmaxf(pm, sc[0][3]), sc[1][0]);
    pm = fmaxf(fmaxf(pm, sc[1][1]), sc[1][2]);
    pm = fmaxf(fmaxf(pm, sc[1][3]), sc[2][0]);
    pm = fmaxf(fmaxf(pm, sc[2][1]), sc[2][2]);
    pm = fmaxf(fmaxf(pm, sc[2][3]), sc[3][0]);
    pm = fmaxf(fmaxf(pm, sc[3][1]), sc[3][2]);
    pm = fmaxf(pm, sc[3][3]);
    pm = fmaxf(pm, __shfl_xor(pm, 16));
    pm = fmaxf(pm, __shfl_xor(pm, 32));
    if (__any(pm > 8.0f)) {
      const float shift = fmaxf(pm, 0.0f);
      m2 += shift;
      const float esc = exp2f(-shift);
      #pragma unroll
      for (int r = 0; r < 4; r++) {
        const float er = __shfl(esc, l4*4 + r);
        #pragma unroll
        for (int dg = 0; dg < 4; dg++) acc[dg][r] *= er;
        accl[r] *= er;
      }
      #pragma unroll
      for (int kg = 0; kg < 4; kg++)
        #pragma unroll
        for (int r = 0; r < 4; r++) sc[kg][r] -= shift;
    }
    #pragma unroll
    for (int kg = 0; kg < 4; kg++)
      #pragma unroll
      for (int r = 0; r < 4; r++)
        sc[kg][r] = exp2f(sc[kg][r]);

    union { short8 s8; uint32_t u[4]; } pu[2];
    #pragma unroll
    for (int pc = 0; pc < 2; pc++) {
      pu[pc].u[0] = pkbf(sc[2*pc][0],   sc[2*pc][1]);
      pu[pc].u[1] = pkbf(sc[2*pc][2],   sc[2*pc][3]);
      pu[pc].u[2] = pkbf(sc[2*pc+1][0], sc[2*pc+1][1]);
      pu[pc].u[3] = pkbf(sc[2*pc+1][2], sc[2*pc+1][3]);
    }
    __builtin_amdgcn_s_setprio(1);
    #pragma unroll
    for (int dg = 0; dg < 4; dg++)
      #pragma unroll
      for (int pc = 0; pc < 2; pc++)
        acc[dg] = __builtin_amdgcn_mfma_f32_16x16x32_bf16(pu[pc].s8, vf[dg][pc], acc[dg], 0, 0, 0);
    #pragma unroll
    for (int pc = 0; pc < 2; pc++)
      accl = __builtin_amdgcn_mfma_f32_16x16x32_bf16(pu[pc].s8, ones, accl, 0, 0, 0);
    __builtin_amdgcn_s_setprio(0);
  }

  float linv[4];
  #pragma unroll
  for (int r = 0; r < 4; r++) linv[r] = 1.0f / accl[r];
  #pragma unroll
  for (int dg = 0; dg < 4; dg++)
    #pragma unroll
    for (int r = 0; r < 4; r++)
      out[(size_t)(b*S_ + q0 + l4*4 + r) * D_ + h*64 + dg*16 + l15] =
          f2bf(acc[dg][r] * linv[r]);
}

// ---------------------------------------------------------------------------
extern "C" void kernel_launch(void* const* d_in, const int* in_sizes, int n_in,
                              void* d_out, int out_size, void* d_ws, size_t ws_size,
                              hipStream_t stream)
{
  const float* x     = (const float*)d_in[0];
  const int*   mask  = (const int*)d_in[1];
  const float* wq_w  = (const float*)d_in[2];
  const float* wq_b  = (const float*)d_in[3];
  const float* wk_w  = (const float*)d_in[4];
  const float* wk_b  = (const float*)d_in[5];
  const float* wv_w  = (const float*)d_in[6];
  const float* wv_b  = (const float*)d_in[7];
  const float* wo_w  = (const float*)d_in[8];
  const float* wo_b  = (const float*)d_in[9];
  const float* ff1_w = (const float*)d_in[10];
  const float* ff1_b = (const float*)d_in[11];
  const float* ff2_w = (const float*)d_in[12];
  const float* ff2_b = (const float*)d_in[13];
  const float* ln1_a = (const float*)d_in[14];
  const float* ln1_b = (const float*)d_in[15];
  const float* ln2_a = (const float*)d_in[16];
  const float* ln2_b = (const float*)d_in[17];

  uint8_t* ws = (uint8_t*)d_ws;
  const size_t MB = 1024 * 1024;
  short* wqkv  = (short*)(ws + 0);        // (3072,1024) bf16 [wq;wk;wv]     6 MB
  short* wob   = (short*)(ws + 6*MB);     // (1024,1024)                     2 MB
  short* ff1b  = (short*)(ws + 8*MB);     // (4096,1024)                     8 MB
  short* ff2b  = (short*)(ws + 16*MB);    // (1024,4096)                     8 MB
  float* maskb = (float*)(ws + 24*MB + 64*1024);   // TOK fp32             16 KB
  int*   mflg  = (int*)(ws + 24*MB + 128*1024);    // TOK/64 ints
  short* h1    = (short*)(ws + 25*MB);    // (4096,1024) bf16                8 MB
  short* attno = (short*)(ws + 25*MB);    // aliases h1 (disjoint lifetimes)
  short* pB    = (short*)(ws + 25*MB);    // FF2 z2 bf16 partial (h2 dead)   8 MB
  short* qkbuf = (short*)(ws + 33*MB);    // (4096,2048) bf16               16 MB
  short* vt    = (short*)(ws + 49*MB);    // (1024,4096) bf16                8 MB
  float* x2    = (float*)(ws + 65*MB);    // (4096,1024) fp32               16 MB
  short* ffa   = (short*)(ws + 33*MB);    // FF1 out (qkbuf/vt dead)        32 MB
  short* pA    = (short*)(ws + 0);        // FF2 z0/z1 bf16 partials        16 MB

  // 1) fused prep: LN1 (4096 blk) + mask (16 blk) + weight cvt (1536 blk)
  prep_kernel<<<TOK + 16 + 1536, 256, 0, stream>>>(
      x, ln1_a, ln1_b, h1, mask, maskb, mflg,
      wq_w, wk_w, wv_w, wo_w, ff1_w, ff2_w, (short*)ws);
  // 2) fused [Q|K|V] projection, 256^2 pipeline (192 blocks x 512 thr)
  qkv_256<<<dim3(3072/256, TOK/256), 512, 0, stream>>>(
      h1, wqkv, qkbuf, vt, wq_b, wk_b, wv_b);
  // 3) flash attention -> attno (bf16, reuses h1 region), 1024 blocks
  attn_kernel<<<dim3(S_/64, H_, B_), 256, 0, stream>>>(qkbuf, vt, maskb, mflg, attno);
  // 4) x2 = x + attno @ wo^T + bo  (fp32, BN=64, r6 structure)
  gemm_bt<3,64><<<dim3(1024/64, TOK/128), 256, 0, stream>>>(
      attno, wob, x2, nullptr, wo_b, x, 1024, 1024, 1024, 1024);
  // 5) LN2: x2 -> h2 (reuses h1 region)
  ln_kernel<<<TOK, 256, 0, stream>>>(x2, ln2_a, ln2_b, h1);
  // 6) ffa = relu(h2 @ ff1^T + b1), 256^2 pipeline (256 blocks x 512 thr)
  ff1_256<<<dim3(FF_/256, TOK/256), 512, 0, stream>>>(h1, ff1b, ffa, ff1_b);
  // 7) FF2 256^2 split-K=4: z0/z1 -> pA (bf16), z2 -> pB (bf16), z3 -> d_out
  ff2_256<<<dim3(1024/256, TOK/256, 4), 512, 0, stream>>>(
      ffa, ff2b, pA, pB, (float*)d_out);
  // 8) out = x2 + b2 + pA[z0] + pA[z1] + pB + out
  combine3_kernel<<<2048, 256, 0, stream>>>(x2, pA, pB, (float*)d_out, ff2_b, TOK * D_);
}

// Round 16
// 240.697 us; speedup vs baseline: 1.0420x; 1.0420x over previous
//
#include <hip/hip_runtime.h>
#include <hip/hip_bf16.h>
#include <stdint.h>

// Problem constants (B=2, S=2048, D=1024, H=16, DK=64, FF=4096)
#define B_   2
#define S_   2048
#define D_   1024
#define H_   16
#define FF_  4096
#define TOK  4096        // B*S
#define EPS_ 1e-5f
#define SC2  0.18033688f  // (1/8) * log2(e) -- folded into Q at projection

typedef __attribute__((ext_vector_type(8))) short short8;
typedef __attribute__((ext_vector_type(4))) short short4_t;
typedef __attribute__((ext_vector_type(4))) float float4_t;

__device__ __forceinline__ short f2bf(float f) {
  union { float f; uint32_t u; } v; v.f = f;
  uint32_t r = v.u + 0x7fffu + ((v.u >> 16) & 1u);
  return (short)(r >> 16);
}

__device__ __forceinline__ float bf2f(short s) {
  union { uint32_t u; float f; } v; v.u = ((uint32_t)(uint16_t)s) << 16; return v.f;
}

// packed f32x2 -> bf16x2 (compiler emits v_cvt_pk_bf16_f32; RNE)
__device__ __forceinline__ uint32_t pkbf(float a, float b) {
  __hip_bfloat162 h = __float22bfloat162_rn(make_float2(a, b));   // x=low=a
  union { __hip_bfloat162 h; uint32_t u; } c; c.h = h; return c.u;
}

__device__ __forceinline__ void gload_lds16(const void* g, void* l) {
  __builtin_amdgcn_global_load_lds(
      (const __attribute__((address_space(1))) void*)g,
      (__attribute__((address_space(3))) void*)l, 16, 0, 0);
}

// ---------------- fused prep: LN1 + mask + weight-cvt (independent work) ---
// blocks [0,4096): LN1 row per block; [4096,4112): mask (256 thr = 4 tiles);
// [4112,5648): grid-stride bf16 conversion of all weights (12M shorts).
__global__ __launch_bounds__(256) void prep_kernel(
    const float* __restrict__ x, const float* __restrict__ ln1a,
    const float* __restrict__ ln1b, short* __restrict__ h1,
    const int* __restrict__ m, float* __restrict__ maskb, int* __restrict__ flags,
    const float* __restrict__ wq, const float* __restrict__ wk,
    const float* __restrict__ wv, const float* __restrict__ wo,
    const float* __restrict__ f1, const float* __restrict__ f2,
    short* __restrict__ wout)
{
  const int blk = blockIdx.x;
  const int tid = threadIdx.x;
  if (blk < TOK) {
    // ---- LN1 (ddof=1, divide by std+eps) ----
    const int row = blk;
    const float4_t v = *(const float4_t*)(x + (size_t)row * D_ + tid * 4);
    float s  = v[0] + v[1] + v[2] + v[3];
    float ss = v[0]*v[0] + v[1]*v[1] + v[2]*v[2] + v[3]*v[3];
    #pragma unroll
    for (int mm = 1; mm < 64; mm <<= 1) { s += __shfl_xor(s, mm); ss += __shfl_xor(ss, mm); }
    __shared__ float red[8];
    const int wave = tid >> 6, lane = tid & 63;
    if (lane == 0) { red[wave] = s; red[4 + wave] = ss; }
    __syncthreads();
    s  = red[0] + red[1] + red[2] + red[3];
    ss = red[4] + red[5] + red[6] + red[7];
    const float mean = s * (1.0f / D_);
    float var = (ss - (float)D_ * mean * mean) * (1.0f / (D_ - 1));
    var = fmaxf(var, 0.0f);
    const float inv = 1.0f / (sqrtf(var) + EPS_);
    short4_t o;
    #pragma unroll
    for (int j = 0; j < 4; j++) {
      float a = ln1a[tid*4 + j], bb = ln1b[tid*4 + j];
      o[j] = f2bf((v[j] - mean) * inv * a + bb);
    }
    *(short4_t*)(h1 + (size_t)row * D_ + tid * 4) = o;
  } else if (blk < TOK + 16) {
    // ---- mask bias + per-64-key-tile flags (one wave = one tile) ----
    const int i = (blk - TOK) * 256 + tid;
    const int mv = m[i];
    maskb[i] = mv ? 0.0f : -1e30f;
    unsigned long long bal = __ballot(mv == 0);
    if ((tid & 63) == 0) flags[i >> 6] = (bal != 0ull) ? 1 : 0;
  } else {
    // ---- weights -> bf16, grid-stride over 12M shorts ----
    const int n4 = (12 << 20) / 4;
    const int nb = gridDim.x - TOK - 16;
    int idx = (blk - TOK - 16) * 256 + tid;
    const int stride = nb * 256;
    for (int j4 = idx; j4 < n4; j4 += stride) {
      const int j = j4 * 4;
      const int seg = j >> 20;
      const float* src; int off;
      if (seg < 4)      { src = (seg == 0) ? wq : (seg == 1) ? wk : (seg == 2) ? wv : wo;
                          off = j & ((1 << 20) - 1); }
      else if (seg < 8) { src = f1; off = j - (4 << 20); }
      else              { src = f2; off = j - (8 << 20); }
      float4_t v = *(const float4_t*)(src + off);
      short4_t o = { f2bf(v[0]), f2bf(v[1]), f2bf(v[2]), f2bf(v[3]) };
      *(short4_t*)(wout + j) = o;
    }
  }
}

// --------- final combine: out = x2 + bias + bf16(p0)+bf16(p1)+bf16(p2) + out
__global__ void combine3_kernel(const float* __restrict__ x2,
                                const short* __restrict__ pA,   // z0 | z1
                                const short* __restrict__ pB,   // z2
                                float* __restrict__ out, const float* __restrict__ bias,
                                int n) {
  int idx = blockIdx.x * blockDim.x + threadIdx.x;
  int stride = gridDim.x * blockDim.x;
  for (int j = idx * 4; j < n; j += stride * 4) {
    float4_t a  = *(const float4_t*)(x2 + j);
    float4_t c  = *(const float4_t*)(out + j);
    float4_t bb = *(const float4_t*)(bias + (j & (D_ - 1)));
    short4_t q0 = *(const short4_t*)(pA + j);
    short4_t q1 = *(const short4_t*)(pA + (4u << 20) + j);
    short4_t q2 = *(const short4_t*)(pB + j);
    float4_t o;
    #pragma unroll
    for (int e = 0; e < 4; e++)
      o[e] = a[e] + c[e] + bb[e] + bf2f(q0[e]) + bf2f(q1[e]) + bf2f(q2[e]);
    *(float4_t*)(out + j) = o;
  }
}

// ---------------- LayerNorm (LN2), f32 in, bf16 out ------------------------
__global__ __launch_bounds__(256) void ln_kernel(
    const float* __restrict__ x, const float* __restrict__ alpha,
    const float* __restrict__ beta, short* __restrict__ out)
{
  const int row = blockIdx.x;
  const int tid = threadIdx.x;
  const float4_t v = *(const float4_t*)(x + (size_t)row * D_ + tid * 4);
  float s  = v[0] + v[1] + v[2] + v[3];
  float ss = v[0]*v[0] + v[1]*v[1] + v[2]*v[2] + v[3]*v[3];
  #pragma unroll
  for (int m = 1; m < 64; m <<= 1) { s += __shfl_xor(s, m); ss += __shfl_xor(ss, m); }
  __shared__ float red[8];
  const int wave = tid >> 6, lane = tid & 63;
  if (lane == 0) { red[wave] = s; red[4 + wave] = ss; }
  __syncthreads();
  s  = red[0] + red[1] + red[2] + red[3];
  ss = red[4] + red[5] + red[6] + red[7];
  const float mean = s * (1.0f / D_);
  float var = (ss - (float)D_ * mean * mean) * (1.0f / (D_ - 1));
  var = fmaxf(var, 0.0f);
  const float inv = 1.0f / (sqrtf(var) + EPS_);
  short4_t o;
  #pragma unroll
  for (int j = 0; j < 4; j++) {
    float a = alpha[tid*4 + j], bb = beta[tid*4 + j];
    o[j] = f2bf((v[j] - mean) * inv * a + bb);
  }
  *(short4_t*)(out + (size_t)row * D_ + tid * 4) = o;
}

// ---------------- 128-tile GEMM (r6 2-buffer structure; WO only) -----------
template<int EPI, int BN>
__global__ __launch_bounds__(256) void gemm_bt(
    const short* __restrict__ A, const short* __restrict__ Bm,
    void* __restrict__ Cout, void* __restrict__ Cout2,
    const float* __restrict__ bias, const float* __restrict__ res,
    int N, int K, int lda, int ldb)
{
  __shared__ __align__(16) short As[2][128][32];
  __shared__ __align__(16) short Bs[2][BN][32];

  const int tid  = threadIdx.x;
  const int wave = tid >> 6, lane = tid & 63;
  const int l15  = lane & 15, l4 = lane >> 4;

  const int gx = gridDim.x, gy = gridDim.y;
  int bid = (blockIdx.z * gy + blockIdx.y) * gx + blockIdx.x;
  const int q8 = (gx * gy * gridDim.z) >> 3;
  bid = (bid & 7) * q8 + (bid >> 3);
  const int n0 = (bid % gx) * BN;
  const int m0 = ((bid / gx) % gy) * 128;
  const int zi = bid / (gx * gy);
  const int koff = zi * K;

  constexpr int MI = (BN == 128) ? 4 : 2;
  const int rb = (BN == 128) ? (wave >> 1) * 64 : wave * 32;
  const int cb = (BN == 128) ? (wave & 1) * 64 : 0;

  float4_t acc[MI][4] = {};

  const int scol = (lane & 3) * 8;
  const short* gA0 = A + (size_t)(m0 + wave*32 + (lane >> 2)) * lda + koff + scol;
  const short* gA1 = gA0 + (size_t)16 * lda;
  const short* gB0;
  const short* gB1 = nullptr;
  if (BN == 128) {
    gB0 = Bm + (size_t)(n0 + wave*32 + (lane >> 2)) * ldb + koff + scol;
    gB1 = gB0 + (size_t)16 * ldb;
  } else {
    gB0 = Bm + (size_t)(n0 + wave*16 + (lane >> 2)) * ldb + koff + scol;
  }

  gload_lds16(gA0, &As[0][wave*32][0]);
  gload_lds16(gA1, &As[0][wave*32 + 16][0]);
  if (BN == 128) {
    gload_lds16(gB0, &Bs[0][wave*32][0]);
    gload_lds16(gB1, &Bs[0][wave*32 + 16][0]);
  } else {
    gload_lds16(gB0, &Bs[0][wave*16][0]);
  }

  for (int k0 = 0; k0 < K; k0 += 32) {
    const int cur = (k0 >> 5) & 1;
    __syncthreads();
    if (k0 + 32 < K) {
      gload_lds16(gA0 + k0 + 32, &As[cur^1][wave*32][0]);
      gload_lds16(gA1 + k0 + 32, &As[cur^1][wave*32 + 16][0]);
      if (BN == 128) {
        gload_lds16(gB0 + k0 + 32, &Bs[cur^1][wave*32][0]);
        gload_lds16(gB1 + k0 + 32, &Bs[cur^1][wave*32 + 16][0]);
      } else {
        gload_lds16(gB0 + k0 + 32, &Bs[cur^1][wave*16][0]);
      }
    }
    short8 af[MI], bf[4];
    #pragma unroll
    for (int i = 0; i < MI; i++)
      af[i] = *(const short8*)&As[cur][rb + i*16 + l15][l4*8];
    #pragma unroll
    for (int i = 0; i < 4; i++)
      bf[i] = *(const short8*)&Bs[cur][cb + i*16 + l15][l4*8];
    #pragma unroll
    for (int mi = 0; mi < MI; mi++)
      #pragma unroll
      for (int ni = 0; ni < 4; ni++)
        acc[mi][ni] = __builtin_amdgcn_mfma_f32_16x16x32_bf16(af[mi], bf[ni], acc[mi][ni], 0, 0, 0);
  }

  const int crow0 = m0 + rb + l4*4;
  const int ccol0 = n0 + cb + l15;
  #pragma unroll
  for (int mi = 0; mi < MI; mi++) {
    #pragma unroll
    for (int ni = 0; ni < 4; ni++) {
      const int col = ccol0 + ni*16;
      const float bc = bias[col];
      #pragma unroll
      for (int r = 0; r < 4; r++) {
        const int row = crow0 + mi*16 + r;
        ((float*)Cout)[(size_t)row * N + col] =
            res[(size_t)row * N + col] + acc[mi][ni][r] + bc;
      }
    }
  }
}

// ============================================================================
// 256x256-tile GEMM core (verified r13/r14)
// ============================================================================
#define G256_DECLS                                                            \
  const int tid = threadIdx.x;                                                \
  const int w = tid >> 6, lane = tid & 63;                                    \
  const int wm = w >> 2, wn = w & 3;                                          \
  const int l15 = lane & 15, l4 = lane >> 4;                                  \
  const int srow = w*8 + (lane >> 3);                                         \
  const int schk = ((lane & 7) ^ (((lane >> 5) & 1) << 1)) * 8;               \
  const int rswz = (l4 ^ (((l15 >> 2) & 1) << 1)) * 8;                        \
  const int aoff = (wm*128 + l15) * 64 + rswz;                                \
  const int boff = (wn*64  + l15) * 64 + rswz;

#define G256_STG(buf_, koff_, LDA_) do {                                      \
    short* da = lds + (buf_)*16384 + w*512;                                   \
    short* db = lds + 32768 + (buf_)*16384 + w*512;                           \
    const short* sa = gA + (koff_);                                           \
    const short* sb = gB + (koff_);                                           \
    gload_lds16(sa,                      da);                                 \
    gload_lds16(sa +  64*(size_t)(LDA_), da + 4096);                          \
    gload_lds16(sa + 128*(size_t)(LDA_), da + 8192);                          \
    gload_lds16(sa + 192*(size_t)(LDA_), da + 12288);                         \
    gload_lds16(sb,                      db);                                 \
    gload_lds16(sb +  64*(size_t)(LDA_), db + 4096);                          \
    gload_lds16(sb + 128*(size_t)(LDA_), db + 8192);                          \
    gload_lds16(sb + 192*(size_t)(LDA_), db + 12288);                         \
  } while (0)

#define G256_LOOP(LDA_)                                                       \
  float4_t acc[8][4] = {};                                                    \
  G256_STG(0, 0, LDA_);                                                       \
  G256_STG(1, 64, LDA_);                                                      \
  for (int t = 0; t < 16; ++t) {                                              \
    const int cur = t & 1;                                                    \
    if (t < 15) asm volatile("s_waitcnt vmcnt(8)" ::: "memory");              \
    else        asm volatile("s_waitcnt vmcnt(0)" ::: "memory");              \
    __builtin_amdgcn_s_barrier();                                             \
    __builtin_amdgcn_sched_barrier(0);                                        \
    const short* La = lds + cur*16384 + aoff;                                 \
    const short* Lb = lds + 32768 + cur*16384 + boff;                         \
    short8 af[4][2], bf0[2][2], bf1[2][2];                                    \
    _Pragma("unroll") for (int mf = 0; mf < 4; mf++)                          \
      _Pragma("unroll") for (int ks = 0; ks < 2; ks++)                        \
        af[mf][ks] = *(const short8*)(La + mf*1024 + ks*32);                  \
    _Pragma("unroll") for (int nf = 0; nf < 2; nf++)                          \
      _Pragma("unroll") for (int ks = 0; ks < 2; ks++)                        \
        bf0[nf][ks] = *(const short8*)(Lb + nf*1024 + ks*32);                 \
    _Pragma("unroll") for (int nf = 0; nf < 2; nf++)                          \
      _Pragma("unroll") for (int ks = 0; ks < 2; ks++)                        \
        bf1[nf][ks] = *(const short8*)(Lb + (2+nf)*1024 + ks*32);             \
    __builtin_amdgcn_s_setprio(1);                                            \
    _Pragma("unroll") for (int mf = 0; mf < 4; mf++)                          \
      _Pragma("unroll") for (int nf = 0; nf < 2; nf++)                        \
        _Pragma("unroll") for (int ks = 0; ks < 2; ks++)                      \
          acc[mf][nf] = __builtin_amdgcn_mfma_f32_16x16x32_bf16(              \
              af[mf][ks], bf0[nf][ks], acc[mf][nf], 0, 0, 0);                 \
    __builtin_amdgcn_s_setprio(0);                                            \
    short8 a2[4][2];                                                          \
    _Pragma("unroll") for (int mf = 0; mf < 4; mf++)                          \
      _Pragma("unroll") for (int ks = 0; ks < 2; ks++)                        \
        a2[mf][ks] = *(const short8*)(La + (4+mf)*1024 + ks*32);              \
    __builtin_amdgcn_s_setprio(1);                                            \
    _Pragma("unroll") for (int mf = 0; mf < 4; mf++)                          \
      _Pragma("unroll") for (int nf = 0; nf < 2; nf++)                        \
        _Pragma("unroll") for (int ks = 0; ks < 2; ks++)                      \
          acc[mf][2+nf] = __builtin_amdgcn_mfma_f32_16x16x32_bf16(            \
              af[mf][ks], bf1[nf][ks], acc[mf][2+nf], 0, 0, 0);               \
    _Pragma("unroll") for (int mf = 0; mf < 4; mf++)                          \
      _Pragma("unroll") for (int nf = 0; nf < 2; nf++)                        \
        _Pragma("unroll") for (int ks = 0; ks < 2; ks++)                      \
          acc[4+mf][2+nf] = __builtin_amdgcn_mfma_f32_16x16x32_bf16(          \
              a2[mf][ks], bf1[nf][ks], acc[4+mf][2+nf], 0, 0, 0);             \
    __builtin_amdgcn_s_setprio(0);                                            \
    __builtin_amdgcn_s_barrier();   /* all waves done reading buf[cur] */     \
    if (t < 14) G256_STG(cur, (t+2)*64, LDA_);                                \
    __builtin_amdgcn_s_setprio(1);                                            \
    _Pragma("unroll") for (int mf = 0; mf < 4; mf++)                          \
      _Pragma("unroll") for (int nf = 0; nf < 2; nf++)                        \
        _Pragma("unroll") for (int ks = 0; ks < 2; ks++)                      \
          acc[4+mf][nf] = __builtin_amdgcn_mfma_f32_16x16x32_bf16(            \
              a2[mf][ks], bf0[nf][ks], acc[4+mf][nf], 0, 0, 0);               \
    __builtin_amdgcn_s_setprio(0);                                            \
  }

// ---------------- FF1 at 256^2: relu(A @ B^T + bias) -> bf16 ---------------
__global__ __launch_bounds__(512, 2) void ff1_256(
    const short* __restrict__ A, const short* __restrict__ Bm,
    short* __restrict__ Cout, const float* __restrict__ bias)
{
  __shared__ __align__(16) short lds[65536];   // 128 KB
  G256_DECLS
  const int gx = gridDim.x;
  int bid = blockIdx.y * gx + blockIdx.x;
  const int q8 = (gx * gridDim.y) >> 3;
  bid = (bid & 7) * q8 + (bid >> 3);
  const int n0 = (bid % gx) * 256;
  const int m0 = (bid / gx) * 256;
  const short* gA = A  + (size_t)(m0 + srow) * 1024 + schk;
  const short* gB = Bm + (size_t)(n0 + srow) * 1024 + schk;

  G256_LOOP(1024)

  #pragma unroll
  for (int mf = 0; mf < 8; mf++) {
    #pragma unroll
    for (int nf = 0; nf < 4; nf++) {
      const int col = n0 + wn*64 + nf*16 + l15;
      const float bc = bias[col];
      #pragma unroll
      for (int r = 0; r < 4; r++) {
        const int row = m0 + wm*128 + mf*16 + l4*4 + r;
        Cout[(size_t)row * FF_ + col] = f2bf(fmaxf(acc[mf][nf][r] + bc, 0.0f));
      }
    }
  }
}

// ---------------- QKV at 256^2: [Q|K|V] = h1 @ wqkv^T + bias ---------------
__global__ __launch_bounds__(512, 2) void qkv_256(
    const short* __restrict__ A, const short* __restrict__ Bm,
    short* __restrict__ qkbuf, short* __restrict__ vt,
    const float* __restrict__ qb, const float* __restrict__ kb,
    const float* __restrict__ vb)
{
  __shared__ __align__(16) short lds[65536];
  G256_DECLS
  const int gx = gridDim.x;   // 12
  int bid = blockIdx.y * gx + blockIdx.x;
  const int q8 = (gx * gridDim.y) >> 3;
  bid = (bid & 7) * q8 + (bid >> 3);
  const int n0 = (bid % gx) * 256;
  const int m0 = (bid / gx) * 256;
  const short* gA = A  + (size_t)(m0 + srow) * 1024 + schk;
  const short* gB = Bm + (size_t)(n0 + srow) * 1024 + schk;

  G256_LOOP(1024)

  const int seg = n0 >> 10;   // 0=Q, 1=K, 2=V (uniform per block)
  if (seg < 2) {
    const float* bb = seg ? kb : qb;
    const float scl = seg ? 1.0f : SC2;
    #pragma unroll
    for (int mf = 0; mf < 8; mf++)
      #pragma unroll
      for (int nf = 0; nf < 4; nf++) {
        const int col = n0 + wn*64 + nf*16 + l15;
        const float bc = bb[col & 1023];
        #pragma unroll
        for (int r = 0; r < 4; r++) {
          const int row = m0 + wm*128 + mf*16 + l4*4 + r;
          qkbuf[(size_t)row * 2048 + col] = f2bf((acc[mf][nf][r] + bc) * scl);
        }
      }
  } else {
    #pragma unroll
    for (int mf = 0; mf < 8; mf++)
      #pragma unroll
      for (int nf = 0; nf < 4; nf++) {
        const int d = n0 + wn*64 + nf*16 + l15 - 2048;
        const float bc = vb[d];
        const int row0 = m0 + wm*128 + mf*16 + l4*4;
        short4_t o = { f2bf(acc[mf][nf][0] + bc), f2bf(acc[mf][nf][1] + bc),
                       f2bf(acc[mf][nf][2] + bc), f2bf(acc[mf][nf][3] + bc) };
        *(short4_t*)&vt[(size_t)d * TOK + row0] = o;
      }
  }
}

// ---------------- FF2 at 256^2, split-K=4 ----------------------------------
__global__ __launch_bounds__(512, 2) void ff2_256(
    const short* __restrict__ A, const short* __restrict__ Bm,
    short* __restrict__ pA, short* __restrict__ pB, float* __restrict__ dout)
{
  __shared__ __align__(16) short lds[65536];
  G256_DECLS
  const int gx = gridDim.x, gy = gridDim.y;   // 4, 16
  int bid = (blockIdx.z * gy + blockIdx.y) * gx + blockIdx.x;
  const int q8 = (gx * gy * gridDim.z) >> 3;
  bid = (bid & 7) * q8 + (bid >> 3);
  const int n0 = (bid % gx) * 256;
  const int m0 = ((bid / gx) % gy) * 256;
  const int zi = bid / (gx * gy);
  const short* gA = A  + (size_t)(m0 + srow) * 4096 + zi*1024 + schk;
  const short* gB = Bm + (size_t)(n0 + srow) * 4096 + zi*1024 + schk;

  G256_LOOP(4096)

  if (zi < 3) {
    short* dst = (zi < 2) ? (pA + (size_t)zi * (4u << 20)) : pB;
    #pragma unroll
    for (int mf = 0; mf < 8; mf++)
      #pragma unroll
      for (int nf = 0; nf < 4; nf++) {
        const int col = n0 + wn*64 + nf*16 + l15;
        #pragma unroll
        for (int r = 0; r < 4; r++) {
          const int row = m0 + wm*128 + mf*16 + l4*4 + r;
          dst[(size_t)row * D_ + col] = f2bf(acc[mf][nf][r]);
        }
      }
  } else {
    #pragma unroll
    for (int mf = 0; mf < 8; mf++)
      #pragma unroll
      for (int nf = 0; nf < 4; nf++) {
        const int col = n0 + wn*64 + nf*16 + l15;
        #pragma unroll
        for (int r = 0; r < 4; r++) {
          const int row = m0 + wm*128 + mf*16 + l4*4 + r;
          dout[(size_t)row * D_ + col] = acc[mf][nf][r];
        }
      }
  }
}

// ---------------- Flash attention (r14 structure, launch_bounds(256,4)) ----
__global__ __launch_bounds__(256, 4) void attn_kernel(
    const short* __restrict__ qk, const short* __restrict__ vt,
    const float* __restrict__ maskb, const int* __restrict__ mflags,
    short* __restrict__ out)
{
  int bid = (blockIdx.z * H_ + blockIdx.y) * (S_/64) + blockIdx.x;
  bid = (bid & 7) * ((B_ * H_ * (S_/64)) >> 3) + (bid >> 3);
  const int qt = bid % (S_/64);
  const int h  = (bid / (S_/64)) % H_;
  const int b  = bid / ((S_/64) * H_);

  const int tid = threadIdx.x, wave = tid >> 6, lane = tid & 63;
  const int l15 = lane & 15, l4 = lane >> 4;
  const int q0 = qt * 64 + wave * 16;

  __shared__ __align__(16) short Kt[2][4096];
  __shared__ __align__(16) short Vt[2][4096];

  short8 qa[2];
  #pragma unroll
  for (int kc = 0; kc < 2; kc++)
    qa[kc] = *(const short8*)&qk[(size_t)(b*S_ + q0 + l15) * 2048 + h*64 + kc*32 + l4*8];

  short8 ones;
  #pragma unroll
  for (int i = 0; i < 8; i++) ones[i] = (short)0x3F80;

  float4_t acc[4];
  #pragma unroll
  for (int dg = 0; dg < 4; dg++) acc[dg] = (float4_t){0.f, 0.f, 0.f, 0.f};
  float4_t accl = (float4_t){0.f, 0.f, 0.f, 0.f};
  float m2 = 0.0f;

  const int r8 = lane >> 3;
  const int ch = (lane & 7) ^ ((r8 & 3) | ((wave & 1) << 2));
  const int sbase = wave * 512;

  #pragma unroll
  for (int i = 0; i < 2; i++) {
    const int row = i*32 + wave*8 + r8;
    gload_lds16(qk + (size_t)(b*S_ + row) * 2048 + 1024 + h*64 + ch*8, &Kt[0][sbase + i*2048]);
    gload_lds16(vt + (size_t)(h*64 + row) * TOK + b*S_ + ch*8,         &Vt[0][sbase + i*2048]);
  }

  int krow[4];
  #pragma unroll
  for (int kg = 0; kg < 4; kg++)
    krow[kg] = 32*(kg>>1) + 8*(l15>>2) + 4*(kg&1) + (l15&3);
  const int gq = (l15 & 3) | (((l15 >> 2) & 1) << 2);
  const int gv = (l15 & 3) | (((l15 >> 3) & 1) << 2);

  for (int t = 0; t < S_/64; t++) {
    const int cur = t & 1;
    __syncthreads();
    if (t + 1 < S_/64) {
      const int k1 = (t + 1) * 64;
      #pragma unroll
      for (int i = 0; i < 2; i++) {
        const int row = i*32 + wave*8 + r8;
        gload_lds16(qk + (size_t)(b*S_ + k1 + row) * 2048 + 1024 + h*64 + ch*8, &Kt[cur^1][sbase + i*2048]);
        gload_lds16(vt + (size_t)(h*64 + row) * TOK + b*S_ + k1 + ch*8,         &Vt[cur^1][sbase + i*2048]);
      }
    }
    const short* Kc = &Kt[cur][0];
    const short* Vc = &Vt[cur][0];

    short8 kf[4][2], vf[4][2];
    #pragma unroll
    for (int kg = 0; kg < 4; kg++)
      #pragma unroll
      for (int kc = 0; kc < 2; kc++)
        kf[kg][kc] = *(const short8*)(Kc + krow[kg]*64 + ((l4 + kc*4) ^ gq) * 8);
    #pragma unroll
    for (int dg = 0; dg < 4; dg++)
      #pragma unroll
      for (int pc = 0; pc < 2; pc++)
        vf[dg][pc] = *(const short8*)(Vc + (dg*16 + l15)*64 + ((l4 + pc*4) ^ gv) * 8);

    const float negm2 = -m2;
    float4_t sc[4];
    #pragma unroll
    for (int kg = 0; kg < 4; kg++)
      sc[kg] = (float4_t){negm2, negm2, negm2, negm2};
    __builtin_amdgcn_s_setprio(1);
    #pragma unroll
    for (int kg = 0; kg < 4; kg++)
      #pragma unroll
      for (int kc = 0; kc < 2; kc++)
        sc[kg] = __builtin_amdgcn_mfma_f32_16x16x32_bf16(kf[kg][kc], qa[kc], sc[kg], 0, 0, 0);
    __builtin_amdgcn_s_setprio(0);

    if (mflags[b*(S_/64) + t]) {
      #pragma unroll
      for (int kg = 0; kg < 4; kg++) {
        float4_t mb = *(const float4_t*)&maskb[b*S_ + t*64 + 32*(kg>>1) + 4*(kg&1) + 8*l4];
        #pragma unroll
        for (int r = 0; r < 4; r++) sc[kg][r] += mb[r];
      }
    }

    float pm = fmaxf(fmaxf(sc[0][0], sc[0][1]), sc[0][2]);
    pm = fmaxf(fmaxf(pm, sc[0][3]), sc[1][0]);
    pm = fmaxf(fmaxf(pm, sc[1][1]), sc[1][2]);
    pm = fmaxf(fmaxf(pm, sc[1][3]), sc[2][0]);
    pm = fmaxf(fmaxf(pm, sc[2][1]), sc[2][2]);
    pm = fmaxf(fmaxf(pm, sc[2][3]), sc[3][0]);
    pm = fmaxf(fmaxf(pm, sc[3][1]), sc[3][2]);
    pm = fmaxf(pm, sc[3][3]);
    pm = fmaxf(pm, __shfl_xor(pm, 16));
    pm = fmaxf(pm, __shfl_xor(pm, 32));
    if (__any(pm > 8.0f)) {
      const float shift = fmaxf(pm, 0.0f);
      m2 += shift;
      const float esc = exp2f(-shift);
      #pragma unroll
      for (int r = 0; r < 4; r++) {
        const float er = __shfl(esc, l4*4 + r);
        #pragma unroll
        for (int dg = 0; dg < 4; dg++) acc[dg][r] *= er;
        accl[r] *= er;
      }
      #pragma unroll
      for (int kg = 0; kg < 4; kg++)
        #pragma unroll
        for (int r = 0; r < 4; r++) sc[kg][r] -= shift;
    }
    #pragma unroll
    for (int kg = 0; kg < 4; kg++)
      #pragma unroll
      for (int r = 0; r < 4; r++)
        sc[kg][r] = exp2f(sc[kg][r]);

    union { short8 s8; uint32_t u[4]; } pu[2];
    #pragma unroll
    for (int pc = 0; pc < 2; pc++) {
      pu[pc].u[0] = pkbf(sc[2*pc][0],   sc[2*pc][1]);
      pu[pc].u[1] = pkbf(sc[2*pc][2],   sc[2*pc][3]);
      pu[pc].u[2] = pkbf(sc[2*pc+1][0], sc[2*pc+1][1]);
      pu[pc].u[3] = pkbf(sc[2*pc+1][2], sc[2*pc+1][3]);
    }
    __builtin_amdgcn_s_setprio(1);
    #pragma unroll
    for (int dg = 0; dg < 4; dg++)
      #pragma unroll
      for (int pc = 0; pc < 2; pc++)
        acc[dg] = __builtin_amdgcn_mfma_f32_16x16x32_bf16(pu[pc].s8, vf[dg][pc], acc[dg], 0, 0, 0);
    #pragma unroll
    for (int pc = 0; pc < 2; pc++)
      accl = __builtin_amdgcn_mfma_f32_16x16x32_bf16(pu[pc].s8, ones, accl, 0, 0, 0);
    __builtin_amdgcn_s_setprio(0);
  }

  float linv[4];
  #pragma unroll
  for (int r = 0; r < 4; r++) linv[r] = 1.0f / accl[r];
  #pragma unroll
  for (int dg = 0; dg < 4; dg++)
    #pragma unroll
    for (int r = 0; r < 4; r++)
      out[(size_t)(b*S_ + q0 + l4*4 + r) * D_ + h*64 + dg*16 + l15] =
          f2bf(acc[dg][r] * linv[r]);
}

// ---------------------------------------------------------------------------
extern "C" void kernel_launch(void* const* d_in, const int* in_sizes, int n_in,
                              void* d_out, int out_size, void* d_ws, size_t ws_size,
                              hipStream_t stream)
{
  const float* x     = (const float*)d_in[0];
  const int*   mask  = (const int*)d_in[1];
  const float* wq_w  = (const float*)d_in[2];
  const float* wq_b  = (const float*)d_in[3];
  const float* wk_w  = (const float*)d_in[4];
  const float* wk_b  = (const float*)d_in[5];
  const float* wv_w  = (const float*)d_in[6];
  const float* wv_b  = (const float*)d_in[7];
  const float* wo_w  = (const float*)d_in[8];
  const float* wo_b  = (const float*)d_in[9];
  const float* ff1_w = (const float*)d_in[10];
  const float* ff1_b = (const float*)d_in[11];
  const float* ff2_w = (const float*)d_in[12];
  const float* ff2_b = (const float*)d_in[13];
  const float* ln1_a = (const float*)d_in[14];
  const float* ln1_b = (const float*)d_in[15];
  const float* ln2_a = (const float*)d_in[16];
  const float* ln2_b = (const float*)d_in[17];

  uint8_t* ws = (uint8_t*)d_ws;
  const size_t MB = 1024 * 1024;
  short* wqkv  = (short*)(ws + 0);        // (3072,1024) bf16 [wq;wk;wv]     6 MB
  short* wob   = (short*)(ws + 6*MB);     // (1024,1024)                     2 MB
  short* ff1b  = (short*)(ws + 8*MB);     // (4096,1024)                     8 MB
  short* ff2b  = (short*)(ws + 16*MB);    // (1024,4096)                     8 MB
  float* maskb = (float*)(ws + 24*MB + 64*1024);   // TOK fp32             16 KB
  int*   mflg  = (int*)(ws + 24*MB + 128*1024);    // TOK/64 ints
  short* h1    = (short*)(ws + 25*MB);    // (4096,1024) bf16                8 MB
  short* attno = (short*)(ws + 25*MB);    // aliases h1 (disjoint lifetimes)
  short* pB    = (short*)(ws + 25*MB);    // FF2 z2 bf16 partial (h2 dead)   8 MB
  short* qkbuf = (short*)(ws + 33*MB);    // (4096,2048) bf16               16 MB
  short* vt    = (short*)(ws + 49*MB);    // (1024,4096) bf16                8 MB
  float* x2    = (float*)(ws + 65*MB);    // (4096,1024) fp32               16 MB
  short* ffa   = (short*)(ws + 33*MB);    // FF1 out (qkbuf/vt dead)        32 MB
  short* pA    = (short*)(ws + 0);        // FF2 z0/z1 bf16 partials        16 MB

  // 1) fused prep: LN1 (4096 blk) + mask (16 blk) + weight cvt (1536 blk)
  prep_kernel<<<TOK + 16 + 1536, 256, 0, stream>>>(
      x, ln1_a, ln1_b, h1, mask, maskb, mflg,
      wq_w, wk_w, wv_w, wo_w, ff1_w, ff2_w, (short*)ws);
  // 2) fused [Q|K|V] projection, 256^2 pipeline (192 blocks x 512 thr)
  qkv_256<<<dim3(3072/256, TOK/256), 512, 0, stream>>>(
      h1, wqkv, qkbuf, vt, wq_b, wk_b, wv_b);
  // 3) flash attention -> attno (bf16, reuses h1 region), 1024 blocks
  attn_kernel<<<dim3(S_/64, H_, B_), 256, 0, stream>>>(qkbuf, vt, maskb, mflg, attno);
  // 4) x2 = x + attno @ wo^T + bo  (fp32, BN=64, r6 structure)
  gemm_bt<3,64><<<dim3(1024/64, TOK/128), 256, 0, stream>>>(
      attno, wob, x2, nullptr, wo_b, x, 1024, 1024, 1024, 1024);
  // 5) LN2: x2 -> h2 (reuses h1 region)
  ln_kernel<<<TOK, 256, 0, stream>>>(x2, ln2_a, ln2_b, h1);
  // 6) ffa = relu(h2 @ ff1^T + b1), 256^2 pipeline (256 blocks x 512 thr)
  ff1_256<<<dim3(FF_/256, TOK/256), 512, 0, stream>>>(h1, ff1b, ffa, ff1_b);
  // 7) FF2 256^2 split-K=4: z0/z1 -> pA (bf16), z2 -> pB (bf16), z3 -> d_out
  ff2_256<<<dim3(1024/256, TOK/256, 4), 512, 0, stream>>>(
      ffa, ff2b, pA, pB, (float*)d_out);
  // 8) out = x2 + b2 + pA[z0] + pA[z1] + pB + out
  combine3_kernel<<<2048, 256, 0, stream>>>(x2, pA, pB, (float*)d_out, ff2_b, TOK * D_);
}